// Round 5
// baseline (146.463 us; speedup 1.0000x reference)
//
#include <hip/hip_runtime.h>

#define ED 256
#define NHEAD 8
#define NPTS 8
#define DHEAD 32
#define QPB 8   // queries per block (2 passes of 4 waves x 1 query)

typedef _Float16 half4v __attribute__((ext_vector_type(4)));

// ---------------------------------------------------------------------------
// Kernel C: feat fp32 -> fp16. Halves the deform kernel's L2 gather volume
// (1.07 GB -> 0.53 GB); each (head,corner) slice becomes 64 B = exactly one
// cache line. fp16 rel err 2^-11 on |feat|<~6 adds <0.003 absmax (thr 0.096).
// ---------------------------------------------------------------------------
__global__ __launch_bounds__(256) void convert_kernel(
    const float4* __restrict__ feat, half4v* __restrict__ feat16, int n4)
{
    int i = blockIdx.x * 256 + threadIdx.x;
    const int stride = gridDim.x * 256;
    for (; i < n4; i += stride) {
        const float4 f = feat[i];
        half4v h;
        h.x = (_Float16)f.x; h.y = (_Float16)f.y;
        h.z = (_Float16)f.z; h.w = (_Float16)f.w;
        feat16[i] = h;
    }
}

// ---------------------------------------------------------------------------
// Kernel A: per-batch precompute (query is [bs,1,ED] broadcast -> offsets and
// softmax weights depend only on batch). K-split matvecs + LDS reduce.
// ws layout per batch: off[128] then aw[64] (192 floats).
// ---------------------------------------------------------------------------
__global__ __launch_bounds__(256) void precompute_kernel(
    const float* __restrict__ query,
    const float* __restrict__ W_off, const float* __restrict__ b_off,
    const float* __restrict__ W_attn, const float* __restrict__ b_attn,
    float* __restrict__ ws)
{
    const int b = blockIdx.x;
    const int t = threadIdx.x;
    __shared__ float sq[ED];
    __shared__ float red[256];
    __shared__ float sattn[64];

    sq[t] = query[b * ED + t];
    __syncthreads();

    {
        const int col  = t & 127;
        const int half = t >> 7;
        const float* Wp = W_off + (size_t)half * 128 * 128 + col;
        const float* qp = sq + half * 128;
        float a0 = 0.f, a1 = 0.f, a2 = 0.f, a3 = 0.f;
        #pragma unroll 8
        for (int k = 0; k < 128; k += 4) {
            a0 = fmaf(qp[k + 0], Wp[(k + 0) * 128], a0);
            a1 = fmaf(qp[k + 1], Wp[(k + 1) * 128], a1);
            a2 = fmaf(qp[k + 2], Wp[(k + 2) * 128], a2);
            a3 = fmaf(qp[k + 3], Wp[(k + 3) * 128], a3);
        }
        red[t] = (a0 + a1) + (a2 + a3);
    }
    __syncthreads();
    if (t < 128) ws[b * 192 + t] = fmaxf(red[t] + red[t + 128] + b_off[t], 0.0f);
    __syncthreads();

    {
        const int col = t & 63;
        const int qtr = t >> 6;
        const float* Wp = W_attn + (size_t)qtr * 64 * 64 + col;
        const float* qp = sq + qtr * 64;
        float a0 = 0.f, a1 = 0.f, a2 = 0.f, a3 = 0.f;
        #pragma unroll 8
        for (int k = 0; k < 64; k += 4) {
            a0 = fmaf(qp[k + 0], Wp[(k + 0) * 64], a0);
            a1 = fmaf(qp[k + 1], Wp[(k + 1) * 64], a1);
            a2 = fmaf(qp[k + 2], Wp[(k + 2) * 64], a2);
            a3 = fmaf(qp[k + 3], Wp[(k + 3) * 64], a3);
        }
        red[t] = (a0 + a1) + (a2 + a3);
    }
    __syncthreads();
    if (t < 64) {
        sattn[t] = fmaxf(red[t] + red[t + 64] + red[t + 128] + red[t + 192]
                         + b_attn[t], 0.0f);
    }
    __syncthreads();
    if (t < 64) {
        const int hh = t >> 3;
        float m = -1e30f;
        #pragma unroll
        for (int p = 0; p < NPTS; ++p) m = fmaxf(m, sattn[hh * NPTS + p]);
        float s = 0.0f;
        #pragma unroll
        for (int p = 0; p < NPTS; ++p) s += expf(sattn[hh * NPTS + p] - m);
        ws[b * 192 + 128 + t] = expf(sattn[t] - m) / s;
    }
}

// ---------------------------------------------------------------------------
// Kernel B v5: fp16 feature gather + 32-bit offset addressing.
//  - Phase 1 stores BYTE offsets (idx*512, fp16 layout) in s_ofs + folded
//    corner weights in s_wt (split arrays, conflict-free b128).
//  - Phase 2 address = uniform SGPR base + (ofs + lane*8): one v_add_u32 per
//    corner, dwordx2 loads (2 VGPR/result) -> cheap to keep 8+ in flight.
//  - fmaf(w, (float)h, acc) -> v_fma_mix, fp32 accumulate.
//  - blockIdx % bs pins batch b to XCD b: its (now 2MB) fp16 feat map is
//    L2-resident on one XCD.
// ---------------------------------------------------------------------------
__global__ __launch_bounds__(256, 4) void deform_attn_kernel(
    const _Float16* __restrict__ feat16, // [bs, nq, NHEAD, DHEAD] fp16
    const float* __restrict__ ref2d,     // [bs, nq, 1, 2]
    const float* __restrict__ query,     // [bs, 1, ED]
    const float* __restrict__ ln_g, const float* __restrict__ ln_b,
    const float* __restrict__ ws,        // [bs, 192]
    const int* __restrict__ Hp, const int* __restrict__ Wp,
    float* __restrict__ out,             // [bs, nq, ED]
    int nq, int bs)
{
    const int blk = blockIdx.x;
    const int b = blk % bs;                    // XCD swizzle
    const int qbase = (blk / bs) * QPB;
    const int t = threadIdx.x;

    __shared__ float s_off[128];
    __shared__ float s_aw[64];
    __shared__ float s_ref[QPB * 2];
    __shared__ uint4  s_ofs[QPB * 64];         // [q][lane]: lane = p*8+h, byte ofs
    __shared__ float4 s_wt [QPB * 64];

    if (t < 128)      s_off[t] = ws[b * 192 + t];
    else if (t < 192) s_aw[t - 128] = ws[b * 192 + t];
    else if (t < 192 + QPB * 2) {
        const int i = t - 192;                 // i = qL*2 + j
        s_ref[i] = ref2d[(b * nq + qbase + (i >> 1)) * 2 + (i & 1)];
    }
    const int H = Hp[0];
    const int W = Wp[0];
    __syncthreads();

    // ---- Phase 1: 8*64 tuples, 2 per thread; lane l -> (p=l>>3, h=l&7) ----
    #pragma unroll
    for (int u = t; u < QPB * 64; u += 256) {
        const int qL = u >> 6;
        const int l  = u & 63;
        const int p  = l >> 3;
        const int h  = l & 7;
        const int hp = h * 8 + p;

        const float x = s_ref[qL * 2 + 0] * (float)W - 0.5f + s_off[hp * 2 + 0];
        const float y = s_ref[qL * 2 + 1] * (float)H - 0.5f + s_off[hp * 2 + 1];
        const float aw = s_aw[hp];

        const float xf = floorf(x);
        const float yf = floorf(y);
        const int ix = (int)xf;
        const int iy = (int)yf;
        const float wx = x - xf;
        const float wy = y - yf;

        const bool vx0 = (ix >= 0) && (ix < W);
        const bool vx1 = (ix + 1 >= 0) && (ix + 1 < W);
        const bool vy0 = (iy >= 0) && (iy < H);
        const bool vy1 = (iy + 1 >= 0) && (iy + 1 < H);
        const int cx0 = min(max(ix, 0), W - 1);
        const int cx1 = min(max(ix + 1, 0), W - 1);
        const int cy0 = min(max(iy, 0), H - 1);
        const int cy1 = min(max(iy + 1, 0), H - 1);

        const int r0 = cy0 * W;
        const int r1 = cy1 * W;
        uint4 ofs;                              // byte offsets, pos stride 512B
        ofs.x = (unsigned)(r0 + cx0) << 9;
        ofs.y = (unsigned)(r0 + cx1) << 9;
        ofs.z = (unsigned)(r1 + cx0) << 9;
        ofs.w = (unsigned)(r1 + cx1) << 9;

        const float awx = aw * wx, awix = aw - awx;     // aw*(1-wx)
        float4 wt;
        wt.x = (vx0 && vy0) ? awix * (1.0f - wy) : 0.0f;
        wt.y = (vx1 && vy0) ? awx  * (1.0f - wy) : 0.0f;
        wt.z = (vx0 && vy1) ? awix * wy          : 0.0f;
        wt.w = (vx1 && vy1) ? awx  * wy          : 0.0f;

        s_ofs[u] = ofs;
        s_wt[u]  = wt;
    }
    __syncthreads();

    // ---- Phase 2: gather, 2-point straight-line batches ----
    const int qL   = t >> 6;
    const int lane = t & 63;

    const char* fb = (const char*)feat16 + (size_t)b * nq * (NHEAD * DHEAD * 2);
    const unsigned lane8 = (unsigned)lane * 8;   // h*64 + c4*8 within position
    const float4 qv = *(const float4*)(query + b * ED + lane * 4);
    const float4 g  = *(const float4*)(ln_g + lane * 4);
    const float4 be = *(const float4*)(ln_b + lane * 4);

    #pragma unroll
    for (int gq = 0; gq < QPB / 4; ++gq) {
        const int qloc = gq * 4 + qL;
        const int q = qbase + qloc;
        const int cb = qloc * 64 + (lane >> 3); // + p*8 per point

        float ax = 0.f, ay = 0.f, az = 0.f, aw4 = 0.f;

        #pragma unroll
        for (int pp = 0; pp < NPTS; pp += 2) {
            const uint4  iA = s_ofs[cb + pp * 8];
            const float4 wA = s_wt [cb + pp * 8];
            const uint4  iB = s_ofs[cb + pp * 8 + 8];
            const float4 wB = s_wt [cb + pp * 8 + 8];

            const half4v a0 = *(const half4v*)(fb + (iA.x + lane8));
            const half4v a1 = *(const half4v*)(fb + (iA.y + lane8));
            const half4v a2 = *(const half4v*)(fb + (iA.z + lane8));
            const half4v a3 = *(const half4v*)(fb + (iA.w + lane8));
            const half4v b0 = *(const half4v*)(fb + (iB.x + lane8));
            const half4v b1 = *(const half4v*)(fb + (iB.y + lane8));
            const half4v b2 = *(const half4v*)(fb + (iB.z + lane8));
            const half4v b3 = *(const half4v*)(fb + (iB.w + lane8));

            ax = fmaf(wA.x, (float)a0.x, ax); ay = fmaf(wA.x, (float)a0.y, ay);
            az = fmaf(wA.x, (float)a0.z, az); aw4 = fmaf(wA.x, (float)a0.w, aw4);
            ax = fmaf(wA.y, (float)a1.x, ax); ay = fmaf(wA.y, (float)a1.y, ay);
            az = fmaf(wA.y, (float)a1.z, az); aw4 = fmaf(wA.y, (float)a1.w, aw4);
            ax = fmaf(wA.z, (float)a2.x, ax); ay = fmaf(wA.z, (float)a2.y, ay);
            az = fmaf(wA.z, (float)a2.z, az); aw4 = fmaf(wA.z, (float)a2.w, aw4);
            ax = fmaf(wA.w, (float)a3.x, ax); ay = fmaf(wA.w, (float)a3.y, ay);
            az = fmaf(wA.w, (float)a3.z, az); aw4 = fmaf(wA.w, (float)a3.w, aw4);

            ax = fmaf(wB.x, (float)b0.x, ax); ay = fmaf(wB.x, (float)b0.y, ay);
            az = fmaf(wB.x, (float)b0.z, az); aw4 = fmaf(wB.x, (float)b0.w, aw4);
            ax = fmaf(wB.y, (float)b1.x, ax); ay = fmaf(wB.y, (float)b1.y, ay);
            az = fmaf(wB.y, (float)b1.z, az); aw4 = fmaf(wB.y, (float)b1.w, aw4);
            ax = fmaf(wB.z, (float)b2.x, ax); ay = fmaf(wB.z, (float)b2.y, ay);
            az = fmaf(wB.z, (float)b2.z, az); aw4 = fmaf(wB.z, (float)b2.w, aw4);
            ax = fmaf(wB.w, (float)b3.x, ax); ay = fmaf(wB.w, (float)b3.y, ay);
            az = fmaf(wB.w, (float)b3.z, az); aw4 = fmaf(wB.w, (float)b3.w, aw4);
        }

        // ---- Phase 3: residual + wave-local LayerNorm ----
        const float r0 = ax + qv.x;
        const float r1 = ay + qv.y;
        const float r2 = az + qv.z;
        const float r3 = aw4 + qv.w;

        float s  = (r0 + r1) + (r2 + r3);
        float ss = fmaf(r0, r0, fmaf(r1, r1, fmaf(r2, r2, r3 * r3)));
        #pragma unroll
        for (int m = 1; m < 64; m <<= 1) {
            s  += __shfl_xor(s, m, 64);
            ss += __shfl_xor(ss, m, 64);
        }
        const float mean = s * (1.0f / ED);
        const float var  = ss * (1.0f / ED) - mean * mean;
        const float inv  = rsqrtf(var + 1e-5f);

        float4 o;
        o.x = (r0 - mean) * inv * g.x + be.x;
        o.y = (r1 - mean) * inv * g.y + be.y;
        o.z = (r2 - mean) * inv * g.z + be.z;
        o.w = (r3 - mean) * inv * g.w + be.w;
        *(float4*)(out + ((size_t)b * nq + q) * ED + lane * 4) = o;
    }
}

extern "C" void kernel_launch(void* const* d_in, const int* in_sizes, int n_in,
                              void* d_out, int out_size, void* d_ws, size_t ws_size,
                              hipStream_t stream)
{
    const float* query  = (const float*)d_in[0];
    const float* feat   = (const float*)d_in[1];
    const float* ref2d  = (const float*)d_in[2];
    const float* W_off  = (const float*)d_in[3];
    const float* b_off  = (const float*)d_in[4];
    const float* W_attn = (const float*)d_in[5];
    const float* b_attn = (const float*)d_in[6];
    const float* ln_g   = (const float*)d_in[7];
    const float* ln_b   = (const float*)d_in[8];
    const int*   Hp     = (const int*)d_in[9];
    const int*   Wp     = (const int*)d_in[10];
    float* out = (float*)d_out;
    float* ws  = (float*)d_ws;

    const int bs = in_sizes[0] / ED;            // 8
    const int nq = in_sizes[2] / (bs * 2);      // h*w = 4096
    const int nfeat = in_sizes[1];              // bs*nq*ED

    // ws layout: [0, 1536) floats = precompute; fp16 feat at byte 8192.
    _Float16* feat16 = (_Float16*)((char*)d_ws + 8192);

    convert_kernel<<<4096, 256, 0, stream>>>((const float4*)feat,
                                             (half4v*)feat16, nfeat / 4);
    precompute_kernel<<<bs, 256, 0, stream>>>(query, W_off, b_off, W_attn, b_attn, ws);
    deform_attn_kernel<<<bs * nq / QPB, 256, 0, stream>>>(feat16, ref2d, query,
                                                          ln_g, ln_b, ws, Hp, Wp,
                                                          out, nq, bs);
}

// Round 6
// 136.142 us; speedup vs baseline: 1.0758x; 1.0758x over previous
//
#include <hip/hip_runtime.h>

#define ED 256
#define NHEAD 8
#define NPTS 8
#define DHEAD 32
#define QPB 8   // queries per block: 4 waves x 2 queries (one per 32-lane half)

typedef _Float16 half4v __attribute__((ext_vector_type(4)));
typedef _Float16 half8v __attribute__((ext_vector_type(8)));

// ---------------------------------------------------------------------------
// Kernel C: feat fp32 -> fp16. Halves deform's L2 gather volume; each
// (head,corner) slice is 64 B. fp16 rel err adds <0.01 absmax (thr 0.096).
// ---------------------------------------------------------------------------
__global__ __launch_bounds__(256) void convert_kernel(
    const float4* __restrict__ feat, half4v* __restrict__ feat16, int n4)
{
    int i = blockIdx.x * 256 + threadIdx.x;
    const int stride = gridDim.x * 256;
    for (; i < n4; i += stride) {
        const float4 f = feat[i];
        half4v h;
        h.x = (_Float16)f.x; h.y = (_Float16)f.y;
        h.z = (_Float16)f.z; h.w = (_Float16)f.w;
        feat16[i] = h;
    }
}

// ---------------------------------------------------------------------------
// Kernel A: per-batch precompute (query is [bs,1,ED] broadcast -> offsets and
// softmax weights depend only on batch). K-split matvecs + LDS reduce.
// ws layout per batch: off[128] then aw[64] (192 floats).
// ---------------------------------------------------------------------------
__global__ __launch_bounds__(256) void precompute_kernel(
    const float* __restrict__ query,
    const float* __restrict__ W_off, const float* __restrict__ b_off,
    const float* __restrict__ W_attn, const float* __restrict__ b_attn,
    float* __restrict__ ws)
{
    const int b = blockIdx.x;
    const int t = threadIdx.x;
    __shared__ float sq[ED];
    __shared__ float red[256];
    __shared__ float sattn[64];

    sq[t] = query[b * ED + t];
    __syncthreads();

    {
        const int col  = t & 127;
        const int half = t >> 7;
        const float* Wp = W_off + (size_t)half * 128 * 128 + col;
        const float* qp = sq + half * 128;
        float a0 = 0.f, a1 = 0.f, a2 = 0.f, a3 = 0.f;
        #pragma unroll 8
        for (int k = 0; k < 128; k += 4) {
            a0 = fmaf(qp[k + 0], Wp[(k + 0) * 128], a0);
            a1 = fmaf(qp[k + 1], Wp[(k + 1) * 128], a1);
            a2 = fmaf(qp[k + 2], Wp[(k + 2) * 128], a2);
            a3 = fmaf(qp[k + 3], Wp[(k + 3) * 128], a3);
        }
        red[t] = (a0 + a1) + (a2 + a3);
    }
    __syncthreads();
    if (t < 128) ws[b * 192 + t] = fmaxf(red[t] + red[t + 128] + b_off[t], 0.0f);
    __syncthreads();

    {
        const int col = t & 63;
        const int qtr = t >> 6;
        const float* Wp = W_attn + (size_t)qtr * 64 * 64 + col;
        const float* qp = sq + qtr * 64;
        float a0 = 0.f, a1 = 0.f, a2 = 0.f, a3 = 0.f;
        #pragma unroll 8
        for (int k = 0; k < 64; k += 4) {
            a0 = fmaf(qp[k + 0], Wp[(k + 0) * 64], a0);
            a1 = fmaf(qp[k + 1], Wp[(k + 1) * 64], a1);
            a2 = fmaf(qp[k + 2], Wp[(k + 2) * 64], a2);
            a3 = fmaf(qp[k + 3], Wp[(k + 3) * 64], a3);
        }
        red[t] = (a0 + a1) + (a2 + a3);
    }
    __syncthreads();
    if (t < 64) {
        sattn[t] = fmaxf(red[t] + red[t + 64] + red[t + 128] + red[t + 192]
                         + b_attn[t], 0.0f);
    }
    __syncthreads();
    if (t < 64) {
        const int hh = t >> 3;
        float m = -1e30f;
        #pragma unroll
        for (int p = 0; p < NPTS; ++p) m = fmaxf(m, sattn[hh * NPTS + p]);
        float s = 0.0f;
        #pragma unroll
        for (int p = 0; p < NPTS; ++p) s += expf(sattn[hh * NPTS + p] - m);
        ws[b * 192 + 128 + t] = expf(sattn[t] - m) / s;
    }
}

// ---------------------------------------------------------------------------
// Kernel B v6: 8 channels/thread, dwordx4 fp16 loads, wave = 2 queries.
//  - lane 0-31 -> query A, 32-63 -> query B; within half: h = l32>>2,
//    c16 = l32&3 (16B chunk of the 64B head slice).
//  - Per wave per point-pair batch: 4 ds_read_b128 + 8 global dwordx4 + 64
//    fma_mix. vs v5: half the load instrs, half the ds_reads, half the
//    waitcnt batches, one epilogue instead of two. Same bytes, same FMAs.
//  - LayerNorm reduce over 32 lanes (shfl_xor m<=16 stays in-half).
//  - blockIdx % bs pins batch b to XCD b: 2MB fp16 map L2-resident.
// ---------------------------------------------------------------------------
__global__ __launch_bounds__(256, 4) void deform_attn_kernel(
    const _Float16* __restrict__ feat16, // [bs, nq, NHEAD, DHEAD] fp16
    const float* __restrict__ ref2d,     // [bs, nq, 1, 2]
    const float* __restrict__ query,     // [bs, 1, ED]
    const float* __restrict__ ln_g, const float* __restrict__ ln_b,
    const float* __restrict__ ws,        // [bs, 192]
    const int* __restrict__ Hp, const int* __restrict__ Wp,
    float* __restrict__ out,             // [bs, nq, ED]
    int nq, int bs)
{
    const int blk = blockIdx.x;
    const int b = blk % bs;                    // XCD swizzle
    const int qbase = (blk / bs) * QPB;
    const int t = threadIdx.x;

    __shared__ float s_off[128];
    __shared__ float s_aw[64];
    __shared__ float s_ref[QPB * 2];
    __shared__ uint4  s_ofs[QPB * 64];         // [q][p*8+h]: byte offsets
    __shared__ float4 s_wt [QPB * 64];         // [q][p*8+h]: folded weights

    if (t < 128)      s_off[t] = ws[b * 192 + t];
    else if (t < 192) s_aw[t - 128] = ws[b * 192 + t];
    else if (t < 192 + QPB * 2) {
        const int i = t - 192;                 // i = qL*2 + j
        s_ref[i] = ref2d[(b * nq + qbase + (i >> 1)) * 2 + (i & 1)];
    }
    const int H = Hp[0];
    const int W = Wp[0];
    __syncthreads();

    // ---- Phase 1: 8*64 tuples, 2 per thread; entry l -> (p=l>>3, h=l&7) ----
    #pragma unroll
    for (int u = t; u < QPB * 64; u += 256) {
        const int qL = u >> 6;
        const int l  = u & 63;
        const int p  = l >> 3;
        const int h  = l & 7;
        const int hp = h * 8 + p;

        const float x = s_ref[qL * 2 + 0] * (float)W - 0.5f + s_off[hp * 2 + 0];
        const float y = s_ref[qL * 2 + 1] * (float)H - 0.5f + s_off[hp * 2 + 1];
        const float aw = s_aw[hp];

        const float xf = floorf(x);
        const float yf = floorf(y);
        const int ix = (int)xf;
        const int iy = (int)yf;
        const float wx = x - xf;
        const float wy = y - yf;

        const bool vx0 = (ix >= 0) && (ix < W);
        const bool vx1 = (ix + 1 >= 0) && (ix + 1 < W);
        const bool vy0 = (iy >= 0) && (iy < H);
        const bool vy1 = (iy + 1 >= 0) && (iy + 1 < H);
        const int cx0 = min(max(ix, 0), W - 1);
        const int cx1 = min(max(ix + 1, 0), W - 1);
        const int cy0 = min(max(iy, 0), H - 1);
        const int cy1 = min(max(iy + 1, 0), H - 1);

        const int r0 = cy0 * W;
        const int r1 = cy1 * W;
        uint4 ofs;                              // byte offsets, pos stride 512B
        ofs.x = (unsigned)(r0 + cx0) << 9;
        ofs.y = (unsigned)(r0 + cx1) << 9;
        ofs.z = (unsigned)(r1 + cx0) << 9;
        ofs.w = (unsigned)(r1 + cx1) << 9;

        const float awx = aw * wx, awix = aw - awx;     // aw*(1-wx)
        float4 wt;
        wt.x = (vx0 && vy0) ? awix * (1.0f - wy) : 0.0f;
        wt.y = (vx1 && vy0) ? awx  * (1.0f - wy) : 0.0f;
        wt.z = (vx0 && vy1) ? awix * wy          : 0.0f;
        wt.w = (vx1 && vy1) ? awx  * wy          : 0.0f;

        s_ofs[u] = ofs;
        s_wt[u]  = wt;
    }
    __syncthreads();

    // ---- Phase 2: gather. wave = 2 queries; thread = 8 channels ----
    const int wave = t >> 6;
    const int lane = t & 63;
    const int half = lane >> 5;
    const int l32  = lane & 31;
    const int h    = l32 >> 2;                 // head
    const int c16  = l32 & 3;                  // 16B chunk within 64B slice
    const int qloc = wave * 2 + half;
    const int q    = qbase + qloc;
    const int cb   = qloc * 64 + h;            // + p*8 per point

    const char* fb = (const char*)feat16 + (size_t)b * nq * (NHEAD * DHEAD * 2);
    const unsigned laneofs = (unsigned)(h * 64 + c16 * 16);

    float acc[8] = {0.f, 0.f, 0.f, 0.f, 0.f, 0.f, 0.f, 0.f};

    #pragma unroll
    for (int pp = 0; pp < NPTS; pp += 2) {
        const uint4  iA = s_ofs[cb + pp * 8];
        const float4 wA = s_wt [cb + pp * 8];
        const uint4  iB = s_ofs[cb + pp * 8 + 8];
        const float4 wB = s_wt [cb + pp * 8 + 8];

        const half8v a0 = *(const half8v*)(fb + (iA.x + laneofs));
        const half8v a1 = *(const half8v*)(fb + (iA.y + laneofs));
        const half8v a2 = *(const half8v*)(fb + (iA.z + laneofs));
        const half8v a3 = *(const half8v*)(fb + (iA.w + laneofs));
        const half8v b0 = *(const half8v*)(fb + (iB.x + laneofs));
        const half8v b1 = *(const half8v*)(fb + (iB.y + laneofs));
        const half8v b2 = *(const half8v*)(fb + (iB.z + laneofs));
        const half8v b3 = *(const half8v*)(fb + (iB.w + laneofs));

        #pragma unroll
        for (int j = 0; j < 8; ++j) {
            acc[j] = fmaf(wA.x, (float)a0[j], acc[j]);
            acc[j] = fmaf(wA.y, (float)a1[j], acc[j]);
            acc[j] = fmaf(wA.z, (float)a2[j], acc[j]);
            acc[j] = fmaf(wA.w, (float)a3[j], acc[j]);
            acc[j] = fmaf(wB.x, (float)b0[j], acc[j]);
            acc[j] = fmaf(wB.y, (float)b1[j], acc[j]);
            acc[j] = fmaf(wB.z, (float)b2[j], acc[j]);
            acc[j] = fmaf(wB.w, (float)b3[j], acc[j]);
        }
    }

    // ---- Phase 3: residual + half-wave (32-lane) LayerNorm ----
    const float4 qv0 = *(const float4*)(query + b * ED + l32 * 8);
    const float4 qv1 = *(const float4*)(query + b * ED + l32 * 8 + 4);
    float r[8];
    r[0] = acc[0] + qv0.x; r[1] = acc[1] + qv0.y;
    r[2] = acc[2] + qv0.z; r[3] = acc[3] + qv0.w;
    r[4] = acc[4] + qv1.x; r[5] = acc[5] + qv1.y;
    r[6] = acc[6] + qv1.z; r[7] = acc[7] + qv1.w;

    float s = 0.f, ss = 0.f;
    #pragma unroll
    for (int j = 0; j < 8; ++j) {
        s += r[j];
        ss = fmaf(r[j], r[j], ss);
    }
    #pragma unroll
    for (int m = 1; m < 32; m <<= 1) {         // stays within 32-lane half
        s  += __shfl_xor(s, m, 64);
        ss += __shfl_xor(ss, m, 64);
    }
    const float mean = s * (1.0f / ED);
    const float var  = ss * (1.0f / ED) - mean * mean;
    const float inv  = rsqrtf(var + 1e-5f);

    const float4 g0  = *(const float4*)(ln_g + l32 * 8);
    const float4 g1  = *(const float4*)(ln_g + l32 * 8 + 4);
    const float4 be0 = *(const float4*)(ln_b + l32 * 8);
    const float4 be1 = *(const float4*)(ln_b + l32 * 8 + 4);

    float4 o0, o1;
    o0.x = (r[0] - mean) * inv * g0.x + be0.x;
    o0.y = (r[1] - mean) * inv * g0.y + be0.y;
    o0.z = (r[2] - mean) * inv * g0.z + be0.z;
    o0.w = (r[3] - mean) * inv * g0.w + be0.w;
    o1.x = (r[4] - mean) * inv * g1.x + be1.x;
    o1.y = (r[5] - mean) * inv * g1.y + be1.y;
    o1.z = (r[6] - mean) * inv * g1.z + be1.z;
    o1.w = (r[7] - mean) * inv * g1.w + be1.w;

    float* op = out + ((size_t)b * nq + q) * ED + l32 * 8;
    *(float4*)op       = o0;
    *(float4*)(op + 4) = o1;
}

extern "C" void kernel_launch(void* const* d_in, const int* in_sizes, int n_in,
                              void* d_out, int out_size, void* d_ws, size_t ws_size,
                              hipStream_t stream)
{
    const float* query  = (const float*)d_in[0];
    const float* feat   = (const float*)d_in[1];
    const float* ref2d  = (const float*)d_in[2];
    const float* W_off  = (const float*)d_in[3];
    const float* b_off  = (const float*)d_in[4];
    const float* W_attn = (const float*)d_in[5];
    const float* b_attn = (const float*)d_in[6];
    const float* ln_g   = (const float*)d_in[7];
    const float* ln_b   = (const float*)d_in[8];
    const int*   Hp     = (const int*)d_in[9];
    const int*   Wp     = (const int*)d_in[10];
    float* out = (float*)d_out;
    float* ws  = (float*)d_ws;

    const int bs = in_sizes[0] / ED;            // 8
    const int nq = in_sizes[2] / (bs * 2);      // h*w = 4096
    const int nfeat = in_sizes[1];              // bs*nq*ED

    // ws layout: [0, 1536) floats = precompute; fp16 feat at byte 8192.
    _Float16* feat16 = (_Float16*)((char*)d_ws + 8192);

    convert_kernel<<<4096, 256, 0, stream>>>((const float4*)feat,
                                             (half4v*)feat16, nfeat / 4);
    precompute_kernel<<<bs, 256, 0, stream>>>(query, W_off, b_off, W_attn, b_attn, ws);
    deform_attn_kernel<<<bs * nq / QPB, 256, 0, stream>>>(feat16, ref2d, query,
                                                          ln_g, ln_b, ws, Hp, Wp,
                                                          out, nq, bs);
}